// Round 1
// baseline (421.343 us; speedup 1.0000x reference)
//
#include <hip/hip_runtime.h>

#define IMG 256
#define TILE 16
#define CHUNK 256
#define FBIG 1e10f
#define BPAD 1e-4f

// Record layout (20 floats, 16 used; stride 20 to spread LDS banks):
// [0]=x1 [1]=y1 [2]=y2-y1 [3]=x2-x1   (edge0: w0 = edge(x1,y1,x2,y2))
// [4]=x2 [5]=y2 [6]=y0-y2 [7]=x0-x2   (edge1)
// [8]=x0 [9]=y0 [10]=y1-y0 [11]=x1-x0 (edge2)
// [12]=z0 [13]=z1 [14]=z2 [15]=denom(=area)

__global__ __launch_bounds__(256) void raster_kernel(
    const float* __restrict__ vertices,  // [B,V,3]
    const int*   __restrict__ faces,     // [F,3]
    float*       __restrict__ out,       // p2f [B,H,W] then bary [B,H,W,3], all as f32
    int B, int V, int F)
{
#pragma clang fp contract(off)
    __shared__ __align__(16) float s_bbox[CHUNK][4];
    __shared__ __align__(16) float s_rec[CHUNK][20];

    const int b    = blockIdx.y;
    const int tile = blockIdx.x;              // 0..255
    const int ti   = tile / (IMG / TILE);
    const int tj   = tile % (IMG / TILE);
    const int tid  = threadIdx.x;
    const int wave = tid >> 6;
    const int lane = tid & 63;

    // wave covers 4 rows x 16 cols
    const int row = ti * TILE + wave * 4 + (lane >> 4);
    const int col = tj * TILE + (lane & 15);
    const float px = 1.0f - (2.0f * (float)col + 1.0f) / 256.0f;
    const float py = 1.0f - (2.0f * (float)row + 1.0f) / 256.0f;

    // wave-uniform pixel coordinate ranges (px,py decrease with index)
    const float px_hi = 1.0f - (2.0f * (float)(tj * TILE) + 1.0f) / 256.0f;
    const float px_lo = 1.0f - (2.0f * (float)(tj * TILE + TILE - 1) + 1.0f) / 256.0f;
    const int   r0    = ti * TILE + wave * 4;
    const float py_hi = 1.0f - (2.0f * (float)r0 + 1.0f) / 256.0f;
    const float py_lo = 1.0f - (2.0f * (float)(r0 + 3) + 1.0f) / 256.0f;

    float bestz = FBIG;
    int   bestf = -1;
    float bw0 = -1.0f, bw1 = -1.0f, bw2 = -1.0f;

    const float* vb = vertices + (size_t)b * V * 3;
    const int nchunks = (F + CHUNK - 1) / CHUNK;

    for (int c = 0; c < nchunks; ++c) {
        __syncthreads();
        // ---- loader: one face per thread ----
        {
            const int f = c * CHUNK + tid;
            bool okf = false;
            float x0=0,y0=0,z0=0,x1=0,y1=0,z1=0,x2=0,y2=0,z2=0,area=0;
            if (f < F) {
                const int i0 = faces[3*f+0], i1 = faces[3*f+1], i2 = faces[3*f+2];
                x0 = -vb[3*i0+0]; y0 = -vb[3*i0+1]; z0 = vb[3*i0+2];
                x1 = -vb[3*i1+0]; y1 = -vb[3*i1+1]; z1 = vb[3*i1+2];
                x2 = -vb[3*i2+0]; y2 = -vb[3*i2+1]; z2 = vb[3*i2+2];
                area = (x1 - x0) * (y2 - y0) - (y1 - y0) * (x2 - x0);
                const float zmax = fmaxf(fmaxf(z0, z1), z2);
                okf = (area > 1e-8f) && (zmax >= 0.0f);
            }
            if (okf) {
                s_bbox[tid][0] = fminf(fminf(x0,x1),x2) - BPAD;
                s_bbox[tid][1] = fmaxf(fmaxf(x0,x1),x2) + BPAD;
                s_bbox[tid][2] = fminf(fminf(y0,y1),y2) - BPAD;
                s_bbox[tid][3] = fmaxf(fmaxf(y0,y1),y2) + BPAD;
                float* r = s_rec[tid];
                r[0]=x1;  r[1]=y1;  r[2]=y2-y1;  r[3]=x2-x1;
                r[4]=x2;  r[5]=y2;  r[6]=y0-y2;  r[7]=x0-x2;
                r[8]=x0;  r[9]=y0;  r[10]=y1-y0; r[11]=x1-x0;
                r[12]=z0; r[13]=z1; r[14]=z2;    r[15]=area;
            } else {
                s_bbox[tid][0] =  4e9f; s_bbox[tid][1] = -4e9f;
                s_bbox[tid][2] =  4e9f; s_bbox[tid][3] = -4e9f;
            }
        }
        __syncthreads();

        // ---- test: per wave, 64-wide bbox prepass + ballot, then per-face broadcast ----
        for (int g = 0; g < CHUNK / 64; ++g) {
            const int fl = g * 64 + lane;
            const float bxmin = s_bbox[fl][0];
            const float bxmax = s_bbox[fl][1];
            const float bymin = s_bbox[fl][2];
            const float bymax = s_bbox[fl][3];
            const bool ov = (bxmin <= px_hi) && (bxmax >= px_lo) &&
                            (bymin <= py_hi) && (bymax >= py_lo);
            unsigned long long mask = __ballot(ov);
            while (mask) {
                const int bit = __builtin_ctzll(mask);
                mask &= mask - 1;
                const float* r = s_rec[g * 64 + bit];  // wave-uniform -> LDS broadcast
                const float e0 = (px - r[0]) * r[2]  - (py - r[1]) * r[3];
                const float e1 = (px - r[4]) * r[6]  - (py - r[5]) * r[7];
                const float e2 = (px - r[8]) * r[10] - (py - r[9]) * r[11];
                if (e0 >= 0.0f && e1 >= 0.0f && e2 >= 0.0f) {
                    const float denom = r[15];
                    const float w0 = e0 / denom;
                    const float w1 = e1 / denom;
                    const float w2 = e2 / denom;
                    const float pz = (w0 * r[12] + w1 * r[13]) + w2 * r[14];
                    if (pz >= 0.0f && pz < bestz) {
                        bestz = pz;
                        bestf = c * CHUNK + g * 64 + bit;
                        bw0 = w0; bw1 = w1; bw2 = w2;
                    }
                }
            }
        }
    }

    // ---- write outputs (every element written unconditionally) ----
    const bool hit = bestz < FBIG;
    const size_t pix  = ((size_t)b * IMG + row) * IMG + col;
    out[pix] = hit ? (float)(bestf + b * F) : -1.0f;
    const size_t boff = (size_t)B * IMG * IMG + pix * 3;
    out[boff + 0] = hit ? bw0 : -1.0f;
    out[boff + 1] = hit ? bw1 : -1.0f;
    out[boff + 2] = hit ? bw2 : -1.0f;
}

extern "C" void kernel_launch(void* const* d_in, const int* in_sizes, int n_in,
                              void* d_out, int out_size, void* d_ws, size_t ws_size,
                              hipStream_t stream) {
    const float* vertices = (const float*)d_in[0];
    const int*   faces    = (const int*)d_in[1];
    float* out = (float*)d_out;

    const int F = in_sizes[1] / 3;
    const int B = 2;
    const int V = in_sizes[0] / (3 * B);

    dim3 grid((IMG / TILE) * (IMG / TILE), B);
    raster_kernel<<<grid, 256, 0, stream>>>(vertices, faces, out, B, V, F);
}